// Round 2
// baseline (1639.411 us; speedup 1.0000x reference)
//
#include <hip/hip_runtime.h>

// GCN encoder: h = relu(x@fcW+fcb); h = relu(gcn(h,W1,b1)); out = relu(gcn(h,W2,b2))
// gcn(x,W,b): t = x@W; out[i] = sum_{e:d=i} t[s_e]*norm_e + t[i]*dinv[i]^2 + b
// norm_e = dinv[s]*ew*dinv[d]; deg = segsum(ew at d) + 1 (self loop)

namespace {
constexpr int NN = 20000;
constexpr int NE = 320000;
constexpr int IN_FT = 256, HID1 = 400, HID2 = 200, OUT_FT = 128;
}

__global__ __launch_bounds__(256) void deg_kernel(const int* __restrict__ dst,
                                                  const float* __restrict__ ew,
                                                  float* __restrict__ deg) {
  int tid = blockIdx.x * 256 + threadIdx.x;
  if (tid < NE) {
    unsafeAtomicAdd(&deg[dst[tid]], ew[tid]);
  } else if (tid < NE + NN) {
    unsafeAtomicAdd(&deg[tid - NE], 1.0f);  // self-loop weight 1
  }
}

__global__ __launch_bounds__(256) void dinv_kernel(float* __restrict__ deg) {
  int i = blockIdx.x * 256 + threadIdx.x;
  if (i < NN) {
    float d = deg[i];
    deg[i] = d > 0.f ? rsqrtf(d) : 0.f;  // in place: deg -> dinv
  }
}

__global__ __launch_bounds__(256) void norm_kernel(const int* __restrict__ src,
                                                   const int* __restrict__ dst,
                                                   const float* __restrict__ ew,
                                                   const float* __restrict__ dinv,
                                                   float* __restrict__ nrm) {
  int e = blockIdx.x * 256 + threadIdx.x;
  if (e < NE) {
    nrm[e] = dinv[src[e]] * ew[e] * dinv[dst[e]];
  }
}

// C[M,Nc] = A[M,K] @ B[K,Nc] (+bias) (relu). 64x64 tile, 256 thr, 4x4/thread.
template <bool BIAS, bool RELU>
__global__ __launch_bounds__(256) void gemm_kernel(const float* __restrict__ A,
                                                   const float* __restrict__ B,
                                                   const float* __restrict__ bias,
                                                   float* __restrict__ C,
                                                   int M, int K, int Nc) {
  __shared__ float As[16][64];  // [k][m] transposed
  __shared__ float Bs[16][64];  // [k][n]
  const int tid = threadIdx.x;
  const int tx = tid & 15, ty = tid >> 4;
  const int m0 = blockIdx.y * 64, n0 = blockIdx.x * 64;
  float acc[4][4] = {};
  for (int k0 = 0; k0 < K; k0 += 16) {
    {  // A tile: thread loads float4 of one row
      int r = tid >> 2, kk = (tid & 3) << 2;
      int m = m0 + r, k = k0 + kk;
      float4 av = make_float4(0.f, 0.f, 0.f, 0.f);
      if (m < M && k + 3 < K)
        av = *reinterpret_cast<const float4*>(A + (size_t)m * K + k);
      As[kk + 0][r] = av.x;
      As[kk + 1][r] = av.y;
      As[kk + 2][r] = av.z;
      As[kk + 3][r] = av.w;
    }
    {  // B tile: fully coalesced float4
      int kk = tid >> 4, c = (tid & 15) << 2;
      int k = k0 + kk, n = n0 + c;
      float4 bv = make_float4(0.f, 0.f, 0.f, 0.f);
      if (k < K && n < Nc)  // Nc % 4 == 0 always here
        bv = *reinterpret_cast<const float4*>(B + (size_t)k * Nc + n);
      *reinterpret_cast<float4*>(&Bs[kk][c]) = bv;
    }
    __syncthreads();
#pragma unroll
    for (int kk = 0; kk < 16; ++kk) {
      float a[4], b[4];
#pragma unroll
      for (int i = 0; i < 4; ++i) a[i] = As[kk][ty * 4 + i];
#pragma unroll
      for (int j = 0; j < 4; ++j) b[j] = Bs[kk][tx * 4 + j];
#pragma unroll
      for (int i = 0; i < 4; ++i)
#pragma unroll
        for (int j = 0; j < 4; ++j) acc[i][j] = fmaf(a[i], b[j], acc[i][j]);
    }
    __syncthreads();
  }
#pragma unroll
  for (int i = 0; i < 4; ++i) {
    int m = m0 + ty * 4 + i;
    int n = n0 + tx * 4;
    if (m < M && n < Nc) {
      float4 v = make_float4(acc[i][0], acc[i][1], acc[i][2], acc[i][3]);
      if (BIAS) {
        float4 b = *reinterpret_cast<const float4*>(bias + n);
        v.x += b.x; v.y += b.y; v.z += b.z; v.w += b.w;
      }
      if (RELU) {
        v.x = fmaxf(v.x, 0.f); v.y = fmaxf(v.y, 0.f);
        v.z = fmaxf(v.z, 0.f); v.w = fmaxf(v.w, 0.f);
      }
      *reinterpret_cast<float4*>(C + (size_t)m * Nc + n) = v;
    }
  }
}

// agg[d] += t[s] * norm, one thread per (edge, 4-feature chunk)
template <int F>
__global__ __launch_bounds__(256) void edge_agg_kernel(const int* __restrict__ src,
                                                       const int* __restrict__ dst,
                                                       const float* __restrict__ nrm,
                                                       const float* __restrict__ t,
                                                       float* __restrict__ agg) {
  constexpr int F4 = F / 4;
  int tid = blockIdx.x * 256 + threadIdx.x;
  int e = tid / F4;
  int c = tid % F4;
  if (e >= NE) return;
  int s = src[e], d = dst[e];
  float w = nrm[e];
  float4 v = *reinterpret_cast<const float4*>(t + (size_t)s * F + c * 4);
  float* base = agg + (size_t)d * F + c * 4;
  unsafeAtomicAdd(base + 0, v.x * w);
  unsafeAtomicAdd(base + 1, v.y * w);
  unsafeAtomicAdd(base + 2, v.z * w);
  unsafeAtomicAdd(base + 3, v.w * w);
}

// out = relu(agg + t*dinv^2 + bias)
template <int F>
__global__ __launch_bounds__(256) void finalize_kernel(const float* __restrict__ agg,
                                                       const float* __restrict__ t,
                                                       const float* __restrict__ dinv,
                                                       const float* __restrict__ bias,
                                                       float* __restrict__ out) {
  constexpr int F4 = F / 4;
  int tid = blockIdx.x * 256 + threadIdx.x;
  if (tid >= NN * F4) return;
  int i = tid / F4;
  int c = (tid % F4) * 4;
  float di = dinv[i];
  float w = di * di;
  float4 a = *reinterpret_cast<const float4*>(agg + (size_t)i * F + c);
  float4 tv = *reinterpret_cast<const float4*>(t + (size_t)i * F + c);
  float4 b = *reinterpret_cast<const float4*>(bias + c);
  float4 o;
  o.x = fmaxf(fmaf(tv.x, w, a.x) + b.x, 0.f);
  o.y = fmaxf(fmaf(tv.y, w, a.y) + b.y, 0.f);
  o.z = fmaxf(fmaf(tv.z, w, a.z) + b.z, 0.f);
  o.w = fmaxf(fmaf(tv.w, w, a.w) + b.w, 0.f);
  *reinterpret_cast<float4*>(out + (size_t)i * F + c) = o;
}

extern "C" void kernel_launch(void* const* d_in, const int* in_sizes, int n_in,
                              void* d_out, int out_size, void* d_ws, size_t ws_size,
                              hipStream_t stream) {
  const float* x = (const float*)d_in[0];
  const int* ei = (const int*)d_in[1];   // int32 per harness conversion
  const float* ea = (const float*)d_in[2];
  const float* fcW = (const float*)d_in[3];
  const float* fcb = (const float*)d_in[4];
  const float* W1 = (const float*)d_in[5];
  const float* b1 = (const float*)d_in[6];
  const float* W2 = (const float*)d_in[7];
  const float* b2 = (const float*)d_in[8];
  const int* srcIdx = ei;        // edge_index[0]
  const int* dstIdx = ei + NE;   // edge_index[1]

  char* ws = (char*)d_ws;
  constexpr size_t MB = 1u << 20;
  float* dinv = (float*)(ws);            // 80 KB
  float* nrm  = (float*)(ws + 1 * MB);   // 1.28 MB
  float* bufA = (float*)(ws + 4 * MB);   // 32 MB: h1 [N,400]; then agg1/h2 [N,200] (16MB) + agg2 [N,128] at +16MB
  float* bufB = (float*)(ws + 36 * MB);  // 16 MB: t1 [N,200]; then t2 [N,128]
  // peak ws use: 52 MB

  float* h1 = bufA;
  float* t1 = bufB;

  // --- normalization (shared by both GCN layers) ---
  hipMemsetAsync(dinv, 0, NN * sizeof(float), stream);
  deg_kernel<<<(NE + NN + 255) / 256, 256, 0, stream>>>(dstIdx, ea, dinv);
  dinv_kernel<<<(NN + 255) / 256, 256, 0, stream>>>(dinv);
  norm_kernel<<<(NE + 255) / 256, 256, 0, stream>>>(srcIdx, dstIdx, ea, dinv, nrm);

  // --- h1 = relu(x @ fcW + fcb) ---
  gemm_kernel<true, true><<<dim3((HID1 + 63) / 64, (NN + 63) / 64), 256, 0, stream>>>(
      x, fcW, fcb, h1, NN, IN_FT, HID1);

  // --- layer 1: t1 = h1 @ W1; aggregate; h2 = relu(agg + t1*dinv^2 + b1) ---
  gemm_kernel<false, false><<<dim3((HID2 + 63) / 64, (NN + 63) / 64), 256, 0, stream>>>(
      h1, W1, nullptr, t1, NN, HID1, HID2);
  // h1 is dead now; reuse bufA for agg1 (in-place finalize -> h2)
  float* agg1 = bufA;
  hipMemsetAsync(agg1, 0, (size_t)NN * HID2 * sizeof(float), stream);
  edge_agg_kernel<HID2><<<(NE * (HID2 / 4) + 255) / 256, 256, 0, stream>>>(
      srcIdx, dstIdx, nrm, t1, agg1);
  finalize_kernel<HID2><<<(NN * (HID2 / 4) + 255) / 256, 256, 0, stream>>>(
      agg1, t1, dinv, b1, agg1);  // in place: agg1 becomes h2

  float* h2 = agg1;                       // [N,200] at bufA
  float* t2 = bufB;                       // t1 dead after finalize
  float* agg2 = (float*)((char*)bufA + 16 * MB);  // [N,128] right after h2

  // --- layer 2: t2 = h2 @ W2; aggregate; out = relu(agg + t2*dinv^2 + b2) ---
  gemm_kernel<false, false><<<dim3((OUT_FT + 63) / 64, (NN + 63) / 64), 256, 0, stream>>>(
      h2, W2, nullptr, t2, NN, HID2, OUT_FT);
  hipMemsetAsync(agg2, 0, (size_t)NN * OUT_FT * sizeof(float), stream);
  edge_agg_kernel<OUT_FT><<<(NE * (OUT_FT / 4) + 255) / 256, 256, 0, stream>>>(
      srcIdx, dstIdx, nrm, t2, agg2);
  finalize_kernel<OUT_FT><<<(NN * (OUT_FT / 4) + 255) / 256, 256, 0, stream>>>(
      agg2, t2, dinv, b2, (float*)d_out);
}

// Round 3
// 351.751 us; speedup vs baseline: 4.6607x; 4.6607x over previous
//
#include <hip/hip_runtime.h>

// GCN encoder: h1 = relu(x@fcW+fcb); h2 = relu(gcn(h1,W1,b1)); out = relu(gcn(h2,W2,b2))
// gcn(x,W,b)[i] = sum_{e:dst=i} (x@W)[src_e]*norm_e + (x@W)[i]*dinv[i]^2 + b
// norm_e = dinv[src]*ew*dinv[dst]; deg = segsum(ew at dst) + 1 (self loop)
// Aggregation strategy: build dst-sorted CSR on device, gather per node (no fp32 atomics).

namespace {
constexpr int NN = 20000;
constexpr int NE = 320000;
constexpr int IN_FT = 256, HID1 = 400, HID2 = 200, OUT_FT = 128;
}

__global__ __launch_bounds__(256) void deg_kernel(const int* __restrict__ dst,
                                                  const float* __restrict__ ew,
                                                  float* __restrict__ deg) {
  int tid = blockIdx.x * 256 + threadIdx.x;
  if (tid < NE) {
    unsafeAtomicAdd(&deg[dst[tid]], ew[tid]);
  } else if (tid < NE + NN) {
    unsafeAtomicAdd(&deg[tid - NE], 1.0f);  // self-loop weight 1
  }
}

__global__ __launch_bounds__(256) void dinv_kernel(float* __restrict__ deg) {
  int i = blockIdx.x * 256 + threadIdx.x;
  if (i < NN) {
    float d = deg[i];
    deg[i] = d > 0.f ? rsqrtf(d) : 0.f;  // in place: deg -> dinv
  }
}

__global__ __launch_bounds__(256) void norm_kernel(const int* __restrict__ src,
                                                   const int* __restrict__ dst,
                                                   const float* __restrict__ ew,
                                                   const float* __restrict__ dinv,
                                                   float* __restrict__ nrm) {
  int e = blockIdx.x * 256 + threadIdx.x;
  if (e < NE) {
    nrm[e] = dinv[src[e]] * ew[e] * dinv[dst[e]];
  }
}

// --- CSR build ---
__global__ __launch_bounds__(256) void count_kernel(const int* __restrict__ dst,
                                                    int* __restrict__ count) {
  int e = blockIdx.x * 256 + threadIdx.x;
  if (e < NE) atomicAdd(&count[dst[e]], 1);
}

// single-block exclusive scan of count[NN] -> rowptr[NN+1]
__global__ __launch_bounds__(1024) void scan_kernel(const int* __restrict__ count,
                                                    int* __restrict__ rowptr) {
  constexpr int CHUNK = (NN + 1023) / 1024;  // 20
  __shared__ int partial[1024];
  const int t = threadIdx.x;
  const int base = t * CHUNK;
  int s = 0;
#pragma unroll
  for (int i = 0; i < CHUNK; ++i) {
    int idx = base + i;
    if (idx < NN) s += count[idx];
  }
  partial[t] = s;
  __syncthreads();
  // inclusive Hillis-Steele scan over 1024 partials
  for (int off = 1; off < 1024; off <<= 1) {
    int v = 0;
    if (t >= off) v = partial[t - off];
    __syncthreads();
    if (t >= off) partial[t] += v;
    __syncthreads();
  }
  int excl = partial[t] - s;  // exclusive prefix for this thread's chunk
#pragma unroll
  for (int i = 0; i < CHUNK; ++i) {
    int idx = base + i;
    if (idx < NN) {
      rowptr[idx] = excl;
      excl += count[idx];
    }
  }
  if (t == 1023) rowptr[NN] = partial[1023];
}

// scatter edges into dst-sorted order: srcS[pos]=src, wS[pos]=norm
__global__ __launch_bounds__(256) void scatter_kernel(const int* __restrict__ src,
                                                      const int* __restrict__ dst,
                                                      const float* __restrict__ nrm,
                                                      int* __restrict__ fill,
                                                      int* __restrict__ srcS,
                                                      float* __restrict__ wS) {
  int e = blockIdx.x * 256 + threadIdx.x;
  if (e >= NE) return;
  int d = dst[e];
  int pos = atomicAdd(&fill[d], 1);
  srcS[pos] = src[e];
  wS[pos] = nrm[e];
}

// C[M,Nc] = A[M,K] @ B[K,Nc] (+bias) (relu). 64x64 tile, 256 thr, 4x4/thread.
template <bool BIAS, bool RELU>
__global__ __launch_bounds__(256) void gemm_kernel(const float* __restrict__ A,
                                                   const float* __restrict__ B,
                                                   const float* __restrict__ bias,
                                                   float* __restrict__ C,
                                                   int M, int K, int Nc) {
  __shared__ float As[16][64];  // [k][m] transposed
  __shared__ float Bs[16][64];  // [k][n]
  const int tid = threadIdx.x;
  const int tx = tid & 15, ty = tid >> 4;
  const int m0 = blockIdx.y * 64, n0 = blockIdx.x * 64;
  float acc[4][4] = {};
  for (int k0 = 0; k0 < K; k0 += 16) {
    {  // A tile
      int r = tid >> 2, kk = (tid & 3) << 2;
      int m = m0 + r, k = k0 + kk;
      float4 av = make_float4(0.f, 0.f, 0.f, 0.f);
      if (m < M && k + 3 < K)
        av = *reinterpret_cast<const float4*>(A + (size_t)m * K + k);
      As[kk + 0][r] = av.x;
      As[kk + 1][r] = av.y;
      As[kk + 2][r] = av.z;
      As[kk + 3][r] = av.w;
    }
    {  // B tile
      int kk = tid >> 4, c = (tid & 15) << 2;
      int k = k0 + kk, n = n0 + c;
      float4 bv = make_float4(0.f, 0.f, 0.f, 0.f);
      if (k < K && n < Nc)
        bv = *reinterpret_cast<const float4*>(B + (size_t)k * Nc + n);
      *reinterpret_cast<float4*>(&Bs[kk][c]) = bv;
    }
    __syncthreads();
#pragma unroll
    for (int kk = 0; kk < 16; ++kk) {
      float a[4], b[4];
#pragma unroll
      for (int i = 0; i < 4; ++i) a[i] = As[kk][ty * 4 + i];
#pragma unroll
      for (int j = 0; j < 4; ++j) b[j] = Bs[kk][tx * 4 + j];
#pragma unroll
      for (int i = 0; i < 4; ++i)
#pragma unroll
        for (int j = 0; j < 4; ++j) acc[i][j] = fmaf(a[i], b[j], acc[i][j]);
    }
    __syncthreads();
  }
#pragma unroll
  for (int i = 0; i < 4; ++i) {
    int m = m0 + ty * 4 + i;
    int n = n0 + tx * 4;
    if (m < M && n < Nc) {
      float4 v = make_float4(acc[i][0], acc[i][1], acc[i][2], acc[i][3]);
      if (BIAS) {
        float4 b = *reinterpret_cast<const float4*>(bias + n);
        v.x += b.x; v.y += b.y; v.z += b.z; v.w += b.w;
      }
      if (RELU) {
        v.x = fmaxf(v.x, 0.f); v.y = fmaxf(v.y, 0.f);
        v.z = fmaxf(v.z, 0.f); v.w = fmaxf(v.w, 0.f);
      }
      *reinterpret_cast<float4*>(C + (size_t)m * Nc + n) = v;
    }
  }
}

// Fused gather-aggregate + self-loop + bias + relu. One 64-lane wave per node.
// out[i,f] = relu( sum_j wS[j]*t[srcS[j],f] + t[i,f]*dinv[i]^2 + bias[f] )
template <int F>
__global__ __launch_bounds__(256) void agg_gather_kernel(const int* __restrict__ rowptr,
                                                         const int* __restrict__ srcS,
                                                         const float* __restrict__ wS,
                                                         const float* __restrict__ t,
                                                         const float* __restrict__ dinv,
                                                         const float* __restrict__ bias,
                                                         float* __restrict__ out) {
  constexpr int NITER = (F + 63) / 64;
  const int wv = threadIdx.x >> 6, lane = threadIdx.x & 63;
  const int node = blockIdx.x * 4 + wv;
  if (node >= NN) return;
  const int beg = rowptr[node], end = rowptr[node + 1];
  float acc[NITER];
#pragma unroll
  for (int i = 0; i < NITER; ++i) acc[i] = 0.f;
  for (int j = beg; j < end; ++j) {
    const int s = srcS[j];
    const float wgt = wS[j];
    const float* row = t + (size_t)s * F;
#pragma unroll
    for (int i = 0; i < NITER; ++i) {
      int f = lane + i * 64;
      if (f < F) acc[i] += row[f] * wgt;
    }
  }
  const float di = dinv[node];
  const float self_w = di * di;
  const float* trow = t + (size_t)node * F;
  float* orow = out + (size_t)node * F;
#pragma unroll
  for (int i = 0; i < NITER; ++i) {
    int f = lane + i * 64;
    if (f < F) {
      float v = fmaf(trow[f], self_w, acc[i]) + bias[f];
      orow[f] = fmaxf(v, 0.f);
    }
  }
}

extern "C" void kernel_launch(void* const* d_in, const int* in_sizes, int n_in,
                              void* d_out, int out_size, void* d_ws, size_t ws_size,
                              hipStream_t stream) {
  const float* x = (const float*)d_in[0];
  const int* ei = (const int*)d_in[1];  // int32 per harness conversion
  const float* ea = (const float*)d_in[2];
  const float* fcW = (const float*)d_in[3];
  const float* fcb = (const float*)d_in[4];
  const float* W1 = (const float*)d_in[5];
  const float* b1 = (const float*)d_in[6];
  const float* W2 = (const float*)d_in[7];
  const float* b2 = (const float*)d_in[8];
  const int* srcIdx = ei;       // edge_index[0]
  const int* dstIdx = ei + NE;  // edge_index[1]

  char* ws = (char*)d_ws;
  constexpr size_t MB = 1u << 20;
  float* dinv = (float*)(ws);            // 80 KB
  float* nrm = (float*)(ws + 1 * MB);    // 1.28 MB
  int* rowptr = (int*)(ws + 3 * MB);     // 80 KB (NN+1)
  int* cnt = (int*)(ws + 4 * MB);        // 80 KB (count, then fill cursor)
  int* srcS = (int*)(ws + 5 * MB);       // 1.28 MB
  float* wS = (float*)(ws + 7 * MB);     // 1.28 MB
  float* bufA = (float*)(ws + 9 * MB);   // 32 MB: h1 [N,400] -> h2 [N,200]
  float* bufB = (float*)(ws + 41 * MB);  // 16 MB: t1 [N,200] -> t2 [N,128]
  // peak ws use: 57 MB

  // --- normalization + CSR (shared by both GCN layers) ---
  hipMemsetAsync(dinv, 0, NN * sizeof(float), stream);
  hipMemsetAsync(cnt, 0, NN * sizeof(int), stream);
  deg_kernel<<<(NE + NN + 255) / 256, 256, 0, stream>>>(dstIdx, ea, dinv);
  dinv_kernel<<<(NN + 255) / 256, 256, 0, stream>>>(dinv);
  norm_kernel<<<(NE + 255) / 256, 256, 0, stream>>>(srcIdx, dstIdx, ea, dinv, nrm);
  count_kernel<<<(NE + 255) / 256, 256, 0, stream>>>(dstIdx, cnt);
  scan_kernel<<<1, 1024, 0, stream>>>(cnt, rowptr);
  hipMemcpyAsync(cnt, rowptr, NN * sizeof(int), hipMemcpyDeviceToDevice, stream);
  scatter_kernel<<<(NE + 255) / 256, 256, 0, stream>>>(srcIdx, dstIdx, nrm, cnt, srcS, wS);

  // --- h1 = relu(x @ fcW + fcb) ---
  float* h1 = bufA;
  gemm_kernel<true, true><<<dim3((HID1 + 63) / 64, (NN + 63) / 64), 256, 0, stream>>>(
      x, fcW, fcb, h1, NN, IN_FT, HID1);

  // --- layer 1: t1 = h1 @ W1; h2 = relu(agg(t1) + t1*dinv^2 + b1) ---
  float* t1 = bufB;
  gemm_kernel<false, false><<<dim3((HID2 + 63) / 64, (NN + 63) / 64), 256, 0, stream>>>(
      h1, W1, nullptr, t1, NN, HID1, HID2);
  float* h2 = bufA;  // h1 dead after t1 GEMM
  agg_gather_kernel<HID2><<<(NN + 3) / 4, 256, 0, stream>>>(
      rowptr, srcS, wS, t1, dinv, b1, h2);

  // --- layer 2: t2 = h2 @ W2; out = relu(agg(t2) + t2*dinv^2 + b2) ---
  float* t2 = bufB;  // t1 dead after agg1
  gemm_kernel<false, false><<<dim3((OUT_FT + 63) / 64, (NN + 63) / 64), 256, 0, stream>>>(
      h2, W2, nullptr, t2, NN, HID2, OUT_FT);
  agg_gather_kernel<OUT_FT><<<(NN + 3) / 4, 256, 0, stream>>>(
      rowptr, srcS, wS, t2, dinv, b2, (float*)d_out);
}